// Round 7
// baseline (7525.218 us; speedup 1.0000x reference)
//
#include <hip/hip_runtime.h>

typedef __attribute__((ext_vector_type(8))) __bf16 bf16x8;
typedef __attribute__((ext_vector_type(4))) float f32x4;
typedef __attribute__((ext_vector_type(2))) float f32x2;
typedef __attribute__((ext_vector_type(4))) unsigned int u32x4;
typedef unsigned int u32;
typedef unsigned long long u64;

#define NSEQ 32
#define TTOT 2048
#define DIM  512
#define HID  512
#define G4   2048
#define NGEMM 224
#define NTILE 8192   // 512 t-slabs x 16 col-tiles

#define AL(p)     __hip_atomic_load((p), __ATOMIC_RELAXED, __HIP_MEMORY_SCOPE_AGENT)
#define AX(p, v)  __hip_atomic_exchange((p), (v), __ATOMIC_RELAXED, __HIP_MEMORY_SCOPE_AGENT)

__device__ __forceinline__ float sigmoidf_(float x) {
    return 1.0f / (1.0f + __expf(-x));
}
__device__ __forceinline__ float tanhf_(float x) {
    return 2.0f / (1.0f + __expf(-2.0f * x)) - 1.0f;
}
__device__ __forceinline__ float bflo(u32 v) { return __builtin_bit_cast(float, v << 16); }
__device__ __forceinline__ float bfhi(u32 v) { return __builtin_bit_cast(float, v & 0xffff0000u); }

// ws layout:
//  WxbT  @ 0        (2 MiB)   bf16 [2048 col][512 k]
//  WhbT  @ 2 MiB    (2 MiB)   bf16 [2048 col][512 k]
//  hcomm @ 4 MiB    (256 KiB) bf16 ring [8 slot][2 grp][16 chunk][16 seq][32 col]
//  sent  @ 4M+256K  (512 B)   u32 [2 grp][16 j][4 wave]
//  doneT @ 4M+257K  (2 KiB)   u32 [512 t-slabs]
//  cstate@ 4M+260K  (64 KiB)
//  AxwB  @ 4M+512K  (256 MiB) bf16 [T*32 rows][2048] (row r = t*32 + n)
// total 273,154,048 B <= proven ws floor 273,285,120 B.

// ---------------- init ----------------
__global__ void lstm_init(const float* __restrict__ Wx, const float* __restrict__ Wh,
                          const float* __restrict__ h0,
                          __bf16* __restrict__ WxbT, __bf16* __restrict__ WhbT,
                          __bf16* __restrict__ hcomm, u32* __restrict__ sent,
                          u32* __restrict__ doneT, float* __restrict__ cstate)
{
    int idx = blockIdx.x * 256 + threadIdx.x;   // 0 .. 2048*512-1
    int c = idx & (G4 - 1);
    int k = idx >> 11;
    WxbT[(size_t)c * DIM + k] = (__bf16)Wx[idx];
    WhbT[(size_t)c * HID + k] = (__bf16)Wh[idx];
    if (idx < NSEQ * HID) {                     // seed slot 0 = h_0
        int seq = idx >> 9, cc = idx & 511;
        int i = seq >> 4, s = seq & 15;
        hcomm[(size_t)i * 8192 + (cc >> 5) * 512 + s * 32 + (cc & 31)] = (__bf16)h0[idx];
        cstate[idx] = 0.0f;
    }
    if (idx < 128) sent[idx] = 0;
    if (idx < 512) doneT[idx] = 0;
}

// ---------------- mono kernel: blocks 0-31 recurrence, 32-255 persistent GEMM --------
__global__ __launch_bounds__(256, 1) void lstm_mono(
    const float* __restrict__ x,      // [32][2048][512] f32
    const __bf16* __restrict__ WxbT,  // [2048][512]
    const float* __restrict__ bvec,   // [2048]
    const __bf16* __restrict__ WhbT,  // [2048][512]
    __bf16* __restrict__ hcomm,
    u32* __restrict__ sent,
    u32* __restrict__ doneT,
    __bf16* __restrict__ AxwB,        // [65536][2048] bf16, row r = t*32+n
    float* __restrict__ cstate,
    float* __restrict__ out)          // [32][2048][512] f32
{
    const int bid  = blockIdx.x;
    const int tid  = threadIdx.x;
    const int w    = tid >> 6;
    const int lane = tid & 63;
    const int l15  = lane & 15;
    const int lq   = lane >> 4;

    __shared__ float P[2][4][16][132];   // rec only

    if (bid >= 32) {
        // ================= persistent xWx GEMM =================
        const int wm = w >> 1, wn = w & 1;
        for (int tile = bid - 32; tile < NTILE; tile += NGEMM) {
            const int ts = tile >> 4;          // t-slab (4 timesteps)
            const int cb = (tile & 15) * 128;
            const int m0 = ts * 128;

            f32x4 acc[4][4] = {};
            const float* xrow[4];
#pragma unroll
            for (int mi = 0; mi < 4; ++mi) {
                int r = m0 + wm * 64 + mi * 16 + l15;
                int t = r >> 5, n = r & 31;
                xrow[mi] = x + ((size_t)n * TTOT + t) * DIM;
            }
            const __bf16* bcol[4];
#pragma unroll
            for (int ni = 0; ni < 4; ++ni)
                bcol[ni] = WxbT + (size_t)(cb + wn * 64 + ni * 16 + l15) * DIM;

            for (int k0 = 0; k0 < DIM; k0 += 32) {
                bf16x8 af[4], bfr[4];
#pragma unroll
                for (int mi = 0; mi < 4; ++mi) {
                    const float* p = xrow[mi] + k0 + lq * 8;
                    f32x4 f0 = *(const f32x4*)p;
                    f32x4 f1 = *(const f32x4*)(p + 4);
                    bf16x8 a;
                    a[0] = (__bf16)f0[0]; a[1] = (__bf16)f0[1]; a[2] = (__bf16)f0[2]; a[3] = (__bf16)f0[3];
                    a[4] = (__bf16)f1[0]; a[5] = (__bf16)f1[1]; a[6] = (__bf16)f1[2]; a[7] = (__bf16)f1[3];
                    af[mi] = a;
                }
#pragma unroll
                for (int ni = 0; ni < 4; ++ni)
                    bfr[ni] = *(const bf16x8*)(bcol[ni] + k0 + lq * 8);
#pragma unroll
                for (int mi = 0; mi < 4; ++mi)
#pragma unroll
                    for (int ni = 0; ni < 4; ++ni)
                        acc[mi][ni] = __builtin_amdgcn_mfma_f32_16x16x32_bf16(af[mi], bfr[ni], acc[mi][ni], 0, 0, 0);
            }

            // epilogue: bf16-pack 4 cols/u64 via 2 shuffles, exchange to coherence point
#pragma unroll
            for (int ni = 0; ni < 4; ++ni) {
                int col = cb + wn * 64 + ni * 16 + l15;
                float bias = bvec[col];
#pragma unroll
                for (int mi = 0; mi < 4; ++mi) {
#pragma unroll
                    for (int jj = 0; jj < 4; ++jj) {
                        int r = m0 + wm * 64 + mi * 16 + lq * 4 + jj;
                        float f = acc[mi][ni][jj] + bias;
                        u32 hb  = (u32)__builtin_bit_cast(unsigned short, (__bf16)f);
                        u32 p01 = hb | ((u32)__shfl_xor((int)hb, 1) << 16);
                        u32 p23 = (u32)__shfl_xor((int)p01, 2);
                        if ((l15 & 3) == 0) {
                            u64 pk = (u64)p01 | ((u64)p23 << 32);
                            u64* dst = (u64*)AxwB + (((size_t)r * G4 + col) >> 2);
                            AX(dst, pk);
                        }
                    }
                }
            }
            __syncthreads();   // drains all threads' exchanges (vmcnt) before signal
            if (tid == 0)
                __hip_atomic_fetch_add(&doneT[ts], 1u, __ATOMIC_RELAXED, __HIP_MEMORY_SCOPE_AGENT);
        }
        return;
    }

    // ================= recurrence =================
    const int i = bid >> 4;
    const int j = bid & 15;

    // B-frags: 8 N-tiles x 4 K-tiles (wave w owns K-tiles/chunks 4w..4w+3)
    bf16x8 bfrag[8][4];
#pragma unroll
    for (int n = 0; n < 8; ++n) {
        const __bf16* base = WhbT
            + (size_t)((n >> 1) * 512 + j * 32 + (n & 1) * 16 + l15) * HID
            + (4 * w) * 32 + lq * 8;
#pragma unroll
        for (int kk = 0; kk < 4; ++kk)
            bfrag[n][kk] = *(const bf16x8*)(base + kk * 32);
    }
#pragma unroll
    for (int n = 0; n < 8; ++n)
#pragma unroll
        for (int kk = 0; kk < 4; ++kk)
            asm volatile("" : "+v"(bfrag[n][kk]));

    const int s   = tid >> 4;
    const int cp  = tid & 15;
    const int seq = i * 16 + s;
    const int hc0 = j * 32 + 2 * cp;
    float c0 = cstate[seq * HID + hc0];
    float c1 = cstate[seq * HID + hc0 + 1];

    const u32* sw = sent + i * 64 + 16 * w;   // this wave's 16 producer sentinels
    int ok_t = -1;          // all slabs <= ok_t>>2 verified
    u32 pv = 0; int pv_ok = 0;

    for (int t = 0; t < TTOT; ++t) {
        // --- Axw slab gate (blocking only at startup) ---
        if (t > ok_t) {
            u32 dv;
            do { dv = AL(&doneT[t >> 2]); } while (dv < 16u);
            ok_t = t | 3;
            pv_ok = 0;
            asm volatile("" ::: "memory");
        }

        // --- Axw prefetch: 4 bf16-pair atomic loads (latency hidden under spin) ---
        const size_t arow = (size_t)(t * 32 + seq) * G4 + hc0;
        u32 a0 = AL((const u32*)(AxwB + arow));
        u32 a1 = AL((const u32*)(AxwB + arow + 512));
        u32 a2 = AL((const u32*)(AxwB + arow + 1024));
        u32 a3 = AL((const u32*)(AxwB + arow + 1536));

        // --- sentinel spin: wave-specific window, 4-deep pipelined polls ---
        {
            int v0 = (int)AL(&sw[l15]);
            int v1 = (int)AL(&sw[l15]);
            int v2 = (int)AL(&sw[l15]);
            int v3 = (int)AL(&sw[l15]);
            while (!__all(v0 >= t)) {
                v0 = v1; v1 = v2; v2 = v3;
                v3 = (int)AL(&sw[l15]);
            }
        }
        asm volatile("" ::: "memory");
        __builtin_amdgcn_sched_barrier(0);

        // --- bulk h read: 8 u64 bypass loads = wave's A-frags ---
        const u64* slotr = (const u64*)hcomm + (size_t)(t & 7) * 4096 + (size_t)i * 2048;
        u64 d[4][2];
#pragma unroll
        for (int kk = 0; kk < 4; ++kk) {
            const u64* p = slotr + (size_t)(4 * w + kk) * 128 + l15 * 8 + lq * 2;
            d[kk][0] = AL(p);
            d[kk][1] = AL(p + 1);
        }

        f32x4 acc[8] = {};
#pragma unroll
        for (int kk = 0; kk < 4; ++kk) {
            u32x4 q = { (u32)d[kk][0], (u32)(d[kk][0] >> 32),
                        (u32)d[kk][1], (u32)(d[kk][1] >> 32) };
            bf16x8 a = __builtin_bit_cast(bf16x8, q);
#pragma unroll
            for (int n = 0; n < 8; ++n)
                acc[n] = __builtin_amdgcn_mfma_f32_16x16x32_bf16(a, bfrag[n][kk], acc[n], 0, 0, 0);
        }

        // --- K-partials to LDS (parity ping-pong), single barrier per step ---
        const int par = t & 1;
#pragma unroll
        for (int n = 0; n < 8; ++n)
#pragma unroll
            for (int jj = 0; jj < 4; ++jj)
                P[par][w][lq * 4 + jj][n * 16 + l15] = acc[n][jj];
        __syncthreads();

        // --- gates ---
        f32x2 sq[4];
#pragma unroll
        for (int q = 0; q < 4; ++q) {
            f32x2 v0 = *(const f32x2*)&P[par][0][s][q * 32 + 2 * cp];
            f32x2 v1 = *(const f32x2*)&P[par][1][s][q * 32 + 2 * cp];
            f32x2 v2 = *(const f32x2*)&P[par][2][s][q * 32 + 2 * cp];
            f32x2 v3 = *(const f32x2*)&P[par][3][s][q * 32 + 2 * cp];
            sq[q].x = (v0.x + v1.x) + (v2.x + v3.x);
            sq[q].y = (v0.y + v1.y) + (v2.y + v3.y);
        }

        float i0 = sigmoidf_(sq[0].x + bflo(a0)), f0 = sigmoidf_(sq[1].x + bflo(a1));
        float o0 = sigmoidf_(sq[2].x + bflo(a2)), g0 = tanhf_(sq[3].x + bflo(a3));
        c0 = f0 * c0 + i0 * g0;
        float h0v = o0 * tanhf_(c0);
        float i1 = sigmoidf_(sq[0].y + bfhi(a0)), f1 = sigmoidf_(sq[1].y + bfhi(a1));
        float o1 = sigmoidf_(sq[2].y + bfhi(a2)), g1 = tanhf_(sq[3].y + bfhi(a3));
        c1 = f1 * c1 + i1 * g1;
        float h1v = o1 * tanhf_(c1);

        // --- publish h_{t+1}, per-wave drain, per-wave sentinel ---
        {
            u32 v01 = (u32)__builtin_bit_cast(unsigned short, (__bf16)h0v)
                    | ((u32)__builtin_bit_cast(unsigned short, (__bf16)h1v) << 16);
            u32 prt = (u32)__shfl_xor((int)v01, 1);
            if (!(cp & 1)) {
                u64 pk = (u64)v01 | ((u64)prt << 32);
                u64* dst = (u64*)hcomm + (size_t)((t + 1) & 7) * 4096
                         + (size_t)i * 2048 + (size_t)j * 128 + s * 8 + (cp >> 1);
                AX(dst, pk);
            }
        }
        asm volatile("s_waitcnt vmcnt(0)" ::: "memory");   // this wave's stores ACKed at IF
        if (lane == 0)
            AX(&sent[i * 64 + j * 4 + w], (u32)(t + 1));

        // --- out store: off the critical path (drained by a later wait) ---
        *(f32x2*)(out + ((size_t)seq * TTOT + t) * HID + hc0) = (f32x2){h0v, h1v};

        // --- doneT probe, software-pipelined by one step (zero stall) ---
        if (pv_ok && pv >= 16u) ok_t += 4;
        {
            int ns = (ok_t + 1) >> 2;
            if (ns < 512) { pv = AL(&doneT[ns]); pv_ok = 1; }
            else pv_ok = 0;
        }
    }

    cstate[seq * HID + hc0]     = c0;
    cstate[seq * HID + hc0 + 1] = c1;
}

extern "C" void kernel_launch(void* const* d_in, const int* in_sizes, int n_in,
                              void* d_out, int out_size, void* d_ws, size_t ws_size,
                              hipStream_t stream)
{
    const float* x  = (const float*)d_in[0];
    const float* h0 = (const float*)d_in[1];
    const float* Wx = (const float*)d_in[2];
    const float* Wh = (const float*)d_in[3];
    const float* b  = (const float*)d_in[4];
    float* out = (float*)d_out;

    char* ws = (char*)d_ws;
    __bf16* WxbT   = (__bf16*)(ws);
    __bf16* WhbT   = (__bf16*)(ws + (2u << 20));
    __bf16* hcomm  = (__bf16*)(ws + (4u << 20));
    u32*    sent   = (u32*)(ws + (4u << 20) + (256u << 10));
    u32*    doneT  = (u32*)(ws + (4u << 20) + (257u << 10));
    float*  cstate = (float*)(ws + (4u << 20) + (260u << 10));
    __bf16* AxwB   = (__bf16*)(ws + (4u << 20) + (512u << 10));

    lstm_init<<<dim3((G4 * DIM) / 256), dim3(256), 0, stream>>>(
        Wx, Wh, h0, WxbT, WhbT, hcomm, sent, doneT, cstate);

    lstm_mono<<<dim3(32 + NGEMM), dim3(256), 0, stream>>>(
        x, WxbT, b, WhbT, hcomm, sent, doneT, AxwB, cstate, out);
}

// Round 9
// 6533.651 us; speedup vs baseline: 1.1518x; 1.1518x over previous
//
#include <hip/hip_runtime.h>

typedef __attribute__((ext_vector_type(8))) __bf16 bf16x8;
typedef __attribute__((ext_vector_type(4))) float f32x4;
typedef __attribute__((ext_vector_type(2))) float f32x2;
typedef __attribute__((ext_vector_type(4))) unsigned int u32x4;
typedef unsigned int u32;
typedef unsigned long long u64;

#define NSEQ 32
#define TTOT 2048
#define DIM  512
#define HID  512
#define G4   2048
#define NGEMM 224
#define NTILE 8192   // 512 t-slabs x 16 col-tiles
#define LEAD  96     // gemm lead window in steps

#define AL(p)     __hip_atomic_load((p), __ATOMIC_RELAXED, __HIP_MEMORY_SCOPE_AGENT)
#define AS(p, v)  __hip_atomic_store((p), (v), __ATOMIC_RELAXED, __HIP_MEMORY_SCOPE_AGENT)
#define AX(p, v)  __hip_atomic_exchange((p), (v), __ATOMIC_RELAXED, __HIP_MEMORY_SCOPE_AGENT)

__device__ __forceinline__ float sigmoidf_(float x) {
    return 1.0f / (1.0f + __expf(-x));
}
__device__ __forceinline__ float tanhf_(float x) {
    return 2.0f / (1.0f + __expf(-2.0f * x)) - 1.0f;
}
__device__ __forceinline__ float bflo(u32 v) { return __builtin_bit_cast(float, v << 16); }
__device__ __forceinline__ float bfhi(u32 v) { return __builtin_bit_cast(float, v & 0xffff0000u); }

// ws layout:
//  WxbT  @ 0        (2 MiB)   bf16 [2048 col][512 k]
//  WhbT  @ 2 MiB    (2 MiB)   bf16 [2048 col][512 k]
//  hcomm @ 4 MiB    (256 KiB) bf16 ring [8 slot][2 grp][16 chunk][16 seq][32 col]
//  sent  @ 4M+256K  (512 B)   u32 [2 grp][16 j][4 wave]   (RMW-published, proven)
//  doneT @ 4M+257K  (2 KiB)   u32 [512 t-slabs]           (RMW)
//  recT  @ 4M+259K  (64 B)    u32 [1]                     (RMW)
//  cstate@ 4M+260K  (64 KiB)
//  AxwB  @ 4M+512K  (256 MiB) bf16 [T*32 rows][2048] (row r = t*32+n), agent-store
// total 273,154,048 B (fits proven ws floor).

// ---------------- init ----------------
__global__ void lstm_init(const float* __restrict__ Wx, const float* __restrict__ Wh,
                          const float* __restrict__ h0,
                          __bf16* __restrict__ WxbT, __bf16* __restrict__ WhbT,
                          __bf16* __restrict__ hcomm, u32* __restrict__ sent,
                          u32* __restrict__ doneT, u32* __restrict__ recT,
                          float* __restrict__ cstate)
{
    int idx = blockIdx.x * 256 + threadIdx.x;   // 0 .. 2048*512-1
    int c = idx & (G4 - 1);
    int k = idx >> 11;
    WxbT[(size_t)c * DIM + k] = (__bf16)Wx[idx];
    WhbT[(size_t)c * HID + k] = (__bf16)Wh[idx];
    if (idx < NSEQ * HID) {                     // seed ring slot 0 = h_0
        int seq = idx >> 9, cc = idx & 511;
        int i = seq >> 4, s = seq & 15;
        hcomm[(size_t)i * 8192 + (cc >> 5) * 512 + s * 32 + (cc & 31)] = (__bf16)h0[idx];
        cstate[idx] = 0.0f;
    }
    if (idx < 128) sent[idx] = 0;
    if (idx < 512) doneT[idx] = 0;
    if (idx < 1)   recT[idx] = 0;
}

// ---------------- mono kernel: blocks 0-31 recurrence, 32-255 persistent GEMM --------
__global__ __launch_bounds__(256, 1) void lstm_mono(
    const float* __restrict__ x,      // [32][2048][512] f32
    const __bf16* __restrict__ WxbT,  // [2048][512]
    const float* __restrict__ bvec,   // [2048]
    const __bf16* __restrict__ WhbT,  // [2048][512]
    __bf16* __restrict__ hcomm,
    u32* __restrict__ sent,
    u32* __restrict__ doneT,
    u32* __restrict__ recT,
    __bf16* __restrict__ AxwB,        // [65536][2048] bf16, row r = t*32+n
    float* __restrict__ cstate,
    float* __restrict__ out)          // [32][2048][512] f32
{
    const int bid  = blockIdx.x;
    const int tid  = threadIdx.x;
    const int w    = tid >> 6;
    const int lane = tid & 63;
    const int l15  = lane & 15;
    const int lq   = lane >> 4;

    __shared__ float P[2][4][16][132];   // rec only

    if (bid >= 32) {
        // ================= persistent xWx GEMM (throttled to rec progress) =========
        const int wm = w >> 1, wn = w & 1;
        for (int tile = bid - 32; tile < NTILE; tile += NGEMM) {
            const int ts = tile >> 4;          // t-slab (4 timesteps)
            const int cb = (tile & 15) * 128;
            const int m0 = ts * 128;

            // throttle: stay at most LEAD steps ahead of the recurrence
            {
                const int need = 4 * ts - LEAD;
                if (need > 0)
                    while ((int)AL(recT) < need) __builtin_amdgcn_s_sleep(8);
            }

            f32x4 acc[4][4] = {};
            const float* xrow[4];
#pragma unroll
            for (int mi = 0; mi < 4; ++mi) {
                int r = m0 + wm * 64 + mi * 16 + l15;
                int t = r >> 5, n = r & 31;
                xrow[mi] = x + ((size_t)n * TTOT + t) * DIM;
            }
            const __bf16* bcol[4];
#pragma unroll
            for (int ni = 0; ni < 4; ++ni)
                bcol[ni] = WxbT + (size_t)(cb + wn * 64 + ni * 16 + l15) * DIM;

            for (int k0 = 0; k0 < DIM; k0 += 32) {
                bf16x8 af[4], bfr[4];
#pragma unroll
                for (int mi = 0; mi < 4; ++mi) {
                    const float* p = xrow[mi] + k0 + lq * 8;
                    f32x4 f0 = *(const f32x4*)p;
                    f32x4 f1 = *(const f32x4*)(p + 4);
                    bf16x8 a;
                    a[0] = (__bf16)f0[0]; a[1] = (__bf16)f0[1]; a[2] = (__bf16)f0[2]; a[3] = (__bf16)f0[3];
                    a[4] = (__bf16)f1[0]; a[5] = (__bf16)f1[1]; a[6] = (__bf16)f1[2]; a[7] = (__bf16)f1[3];
                    af[mi] = a;
                }
#pragma unroll
                for (int ni = 0; ni < 4; ++ni)
                    bfr[ni] = *(const bf16x8*)(bcol[ni] + k0 + lq * 8);
#pragma unroll
                for (int mi = 0; mi < 4; ++mi)
#pragma unroll
                    for (int ni = 0; ni < 4; ++ni)
                        acc[mi][ni] = __builtin_amdgcn_mfma_f32_16x16x32_bf16(af[mi], bfr[ni], acc[mi][ni], 0, 0, 0);
            }

            // epilogue: bf16-pack 4 cols/u64, agent-scope STORE (no RMW flood)
#pragma unroll
            for (int ni = 0; ni < 4; ++ni) {
                int col = cb + wn * 64 + ni * 16 + l15;
                float bias = bvec[col];
#pragma unroll
                for (int mi = 0; mi < 4; ++mi) {
#pragma unroll
                    for (int jj = 0; jj < 4; ++jj) {
                        int r = m0 + wm * 64 + mi * 16 + lq * 4 + jj;
                        float f = acc[mi][ni][jj] + bias;
                        u32 hb  = (u32)__builtin_bit_cast(unsigned short, (__bf16)f);
                        u32 p01 = hb | ((u32)__shfl_xor((int)hb, 1) << 16);
                        u32 p23 = (u32)__shfl_xor((int)p01, 2);
                        if ((l15 & 3) == 0) {
                            u64 pk = (u64)p01 | ((u64)p23 << 32);
                            AS((u64*)AxwB + (((size_t)r * G4 + col) >> 2), pk);
                        }
                    }
                }
            }
            __syncthreads();   // drains all threads' stores (vmcnt) before signal
            if (tid == 0)
                __hip_atomic_fetch_add(&doneT[ts], 1u, __ATOMIC_RELAXED, __HIP_MEMORY_SCOPE_AGENT);
        }
        return;
    }

    // ================= recurrence =================
    const int i = bid >> 4;
    const int j = bid & 15;

    // B-frags: 8 N-tiles x 4 K-tiles (wave w owns K-tiles/chunks 4w..4w+3)
    bf16x8 bfrag[8][4];
#pragma unroll
    for (int n = 0; n < 8; ++n) {
        const __bf16* base = WhbT
            + (size_t)((n >> 1) * 512 + j * 32 + (n & 1) * 16 + l15) * HID
            + (4 * w) * 32 + lq * 8;
#pragma unroll
        for (int kk = 0; kk < 4; ++kk)
            bfrag[n][kk] = *(const bf16x8*)(base + kk * 32);
    }
#pragma unroll
    for (int n = 0; n < 8; ++n)
#pragma unroll
        for (int kk = 0; kk < 4; ++kk)
            asm volatile("" : "+v"(bfrag[n][kk]));

    const int s   = tid >> 4;
    const int cp  = tid & 15;
    const int seq = i * 16 + s;
    const int hc0 = j * 32 + 2 * cp;
    float c0 = cstate[seq * HID + hc0];
    float c1 = cstate[seq * HID + hc0 + 1];

    const u32* sw = sent + i * 64 + 16 * w;   // this wave's 16 producer sentinels
    int ok_t = -1;
    u32 pv = 0; int pv_ok = 0;

    for (int t = 0; t < TTOT; ++t) {
        // --- Axw slab gate (blocking only at startup) ---
        if (t > ok_t) {
            u32 dv;
            do { dv = AL(&doneT[t >> 2]); } while (dv < 16u);
            ok_t = t | 3;
            pv_ok = 0;
            asm volatile("" ::: "memory");
        }

        // --- Axw prefetch: 4 bypass loads (latency hidden under spin) ---
        const size_t arow = (size_t)(t * 32 + seq) * G4 + hc0;
        u32 a0 = AL((const u32*)(AxwB + arow));
        u32 a1 = AL((const u32*)(AxwB + arow + 512));
        u32 a2 = AL((const u32*)(AxwB + arow + 1024));
        u32 a3 = AL((const u32*)(AxwB + arow + 1536));

        // --- sentinel spin: wave-specific window, 4-deep pipelined polls ---
        {
            int v0 = (int)AL(&sw[l15]);
            int v1 = (int)AL(&sw[l15]);
            int v2 = (int)AL(&sw[l15]);
            int v3 = (int)AL(&sw[l15]);
            while (!__all(v0 >= t)) {
                v0 = v1; v1 = v2; v2 = v3;
                v3 = (int)AL(&sw[l15]);
            }
        }
        asm volatile("" ::: "memory");
        __builtin_amdgcn_sched_barrier(0);

        // --- bulk h read: 8 u64 bypass loads = wave's A-frags ---
        const u64* slotr = (const u64*)hcomm + (size_t)(t & 7) * 4096 + (size_t)i * 2048;
        u64 d[4][2];
#pragma unroll
        for (int kk = 0; kk < 4; ++kk) {
            const u64* p = slotr + (size_t)(4 * w + kk) * 128 + l15 * 8 + lq * 2;
            d[kk][0] = AL(p);
            d[kk][1] = AL(p + 1);
        }

        f32x4 acc[8] = {};
#pragma unroll
        for (int kk = 0; kk < 4; ++kk) {
            u32x4 q = { (u32)d[kk][0], (u32)(d[kk][0] >> 32),
                        (u32)d[kk][1], (u32)(d[kk][1] >> 32) };
            bf16x8 a = __builtin_bit_cast(bf16x8, q);
#pragma unroll
            for (int n = 0; n < 8; ++n)
                acc[n] = __builtin_amdgcn_mfma_f32_16x16x32_bf16(a, bfrag[n][kk], acc[n], 0, 0, 0);
        }

        // --- K-partials to LDS (parity ping-pong), single barrier per step ---
        const int par = t & 1;
#pragma unroll
        for (int n = 0; n < 8; ++n)
#pragma unroll
            for (int jj = 0; jj < 4; ++jj)
                P[par][w][lq * 4 + jj][n * 16 + l15] = acc[n][jj];
        __syncthreads();

        // --- gates ---
        f32x2 sq[4];
#pragma unroll
        for (int q = 0; q < 4; ++q) {
            f32x2 v0 = *(const f32x2*)&P[par][0][s][q * 32 + 2 * cp];
            f32x2 v1 = *(const f32x2*)&P[par][1][s][q * 32 + 2 * cp];
            f32x2 v2 = *(const f32x2*)&P[par][2][s][q * 32 + 2 * cp];
            f32x2 v3 = *(const f32x2*)&P[par][3][s][q * 32 + 2 * cp];
            sq[q].x = (v0.x + v1.x) + (v2.x + v3.x);
            sq[q].y = (v0.y + v1.y) + (v2.y + v3.y);
        }

        float i0 = sigmoidf_(sq[0].x + bflo(a0)), f0 = sigmoidf_(sq[1].x + bflo(a1));
        float o0 = sigmoidf_(sq[2].x + bflo(a2)), g0 = tanhf_(sq[3].x + bflo(a3));
        c0 = f0 * c0 + i0 * g0;
        float h0v = o0 * tanhf_(c0);
        float i1 = sigmoidf_(sq[0].y + bfhi(a0)), f1 = sigmoidf_(sq[1].y + bfhi(a1));
        float o1 = sigmoidf_(sq[2].y + bfhi(a2)), g1 = tanhf_(sq[3].y + bfhi(a3));
        c1 = f1 * c1 + i1 * g1;
        float h1v = o1 * tanhf_(c1);

        // --- publish h_{t+1}: agent-scope store (visible to bypass loads, no RMW) ---
        {
            u32 v01 = (u32)__builtin_bit_cast(unsigned short, (__bf16)h0v)
                    | ((u32)__builtin_bit_cast(unsigned short, (__bf16)h1v) << 16);
            u32 prt = (u32)__shfl_xor((int)v01, 1);
            if (!(cp & 1)) {
                u64 pk = (u64)v01 | ((u64)prt << 32);
                AS((u64*)hcomm + (size_t)((t + 1) & 7) * 4096
                       + (size_t)i * 2048 + (size_t)j * 128 + s * 8 + (cp >> 1), pk);
            }
        }
        asm volatile("s_waitcnt vmcnt(0)" ::: "memory");   // this wave's stores ACKed
        if (lane == 0)
            AX(&sent[i * 64 + j * 4 + w], (u32)(t + 1));   // proven RMW path
        if (bid == 0 && tid == 0)
            AX(recT, (u32)(t + 1));                        // rec progress for throttle

        // --- out store: off the critical path ---
        *(f32x2*)(out + ((size_t)seq * TTOT + t) * HID + hc0) = (f32x2){h0v, h1v};

        // --- doneT probe, software-pipelined (zero stall in steady state) ---
        if (pv_ok && pv >= 16u) ok_t += 4;
        {
            int ns = (ok_t + 1) >> 2;
            if (ns < 512) { pv = AL(&doneT[ns]); pv_ok = 1; }
            else pv_ok = 0;
        }
    }

    cstate[seq * HID + hc0]     = c0;
    cstate[seq * HID + hc0 + 1] = c1;
}

extern "C" void kernel_launch(void* const* d_in, const int* in_sizes, int n_in,
                              void* d_out, int out_size, void* d_ws, size_t ws_size,
                              hipStream_t stream)
{
    const float* x  = (const float*)d_in[0];
    const float* h0 = (const float*)d_in[1];
    const float* Wx = (const float*)d_in[2];
    const float* Wh = (const float*)d_in[3];
    const float* b  = (const float*)d_in[4];
    float* out = (float*)d_out;

    char* ws = (char*)d_ws;
    __bf16* WxbT   = (__bf16*)(ws);
    __bf16* WhbT   = (__bf16*)(ws + (2u << 20));
    __bf16* hcomm  = (__bf16*)(ws + (4u << 20));
    u32*    sent   = (u32*)(ws + (4u << 20) + (256u << 10));
    u32*    doneT  = (u32*)(ws + (4u << 20) + (257u << 10));
    u32*    recT   = (u32*)(ws + (4u << 20) + (259u << 10));
    float*  cstate = (float*)(ws + (4u << 20) + (260u << 10));
    __bf16* AxwB   = (__bf16*)(ws + (4u << 20) + (512u << 10));

    lstm_init<<<dim3((G4 * DIM) / 256), dim3(256), 0, stream>>>(
        Wx, Wh, h0, WxbT, WhbT, hcomm, sent, doneT, recT, cstate);

    lstm_mono<<<dim3(256), dim3(256), 0, stream>>>(
        x, WxbT, b, WhbT, hcomm, sent, doneT, recT, AxwB, cstate, out);
}